// Round 8
// baseline (521.002 us; speedup 1.0000x reference)
//
#include <hip/hip_runtime.h>
#include <hip/hip_bf16.h>

typedef unsigned long long u64;
typedef __bf16 bf16x8 __attribute__((ext_vector_type(8)));
typedef float f32x4 __attribute__((ext_vector_type(4)));
typedef unsigned short ushort8_t __attribute__((ext_vector_type(8)));

#define TOKS 8192
#define DMODEL 2048
#define FD 1024
#define NEXP 7
#define CAP 1170
#define CAPP 1280
// unified row tiles at 256 rows: 32 shared + 7*5 routed = 67
#define URT256 67

#define MFMA16(a, b, c) __builtin_amdgcn_mfma_f32_16x16x32_bf16(a, b, c, 0, 0, 0)

__device__ __forceinline__ unsigned short f2bf(float f) {
  __hip_bfloat16 b = __float2bfloat16(f);
  return __builtin_bit_cast(unsigned short, b);
}
__device__ __forceinline__ float bf2f(unsigned short u) {
  __hip_bfloat16 b = __builtin_bit_cast(__hip_bfloat16, u);
  return __bfloat162float(b);
}
__device__ __forceinline__ void gload_lds16(const void* g, void* l) {
  __builtin_amdgcn_global_load_lds(
      (const __attribute__((address_space(1))) void*)g,
      (__attribute__((address_space(3))) void*)l, 16, 0, 0);
}

// ---------------- fused x fp32->bf16 convert + gating (1 block = 1 token) ----------------
__global__ __launch_bounds__(256) void k_conv_gate(
    const float* __restrict__ x, const float* __restrict__ gw,
    const float* __restrict__ bias, unsigned short* __restrict__ xb,
    u64* __restrict__ keys) {
  const int t = blockIdx.x;
  const int tid = threadIdx.x;
  const int lane = tid & 63, wv = tid >> 6;
  const float* xr = x + (long)t * DMODEL;
  const int i0 = tid * 8;
  float4 v0 = *(const float4*)&xr[i0];
  float4 v1 = *(const float4*)&xr[i0 + 4];
  float xv[8] = {v0.x, v0.y, v0.z, v0.w, v1.x, v1.y, v1.z, v1.w};
  ushort8_t o;
#pragma unroll
  for (int j = 0; j < 8; ++j) o[j] = f2bf(xv[j]);
  *(ushort8_t*)&xb[(long)t * DMODEL + i0] = o;
  double acc[NEXP];
#pragma unroll
  for (int e = 0; e < NEXP; ++e) acc[e] = 0.0;
#pragma unroll
  for (int j = 0; j < 8; ++j) {
    const float* g = gw + (long)(i0 + j) * NEXP;
    double xd = (double)xv[j];
#pragma unroll
    for (int e = 0; e < NEXP; ++e) acc[e] += xd * (double)g[e];
  }
#pragma unroll
  for (int e = 0; e < NEXP; ++e)
    for (int off = 32; off > 0; off >>= 1)
      acc[e] += __shfl_down(acc[e], off, 64);
  __shared__ double red[4][NEXP];
  if (lane == 0)
#pragma unroll
    for (int e = 0; e < NEXP; ++e) red[wv][e] = acc[e];
  __syncthreads();
  if (tid == 0) {
    float aff[NEXP];
#pragma unroll
    for (int e = 0; e < NEXP; ++e) {
      double lg = red[0][e] + red[1][e] + red[2][e] + red[3][e] + (double)bias[e];
      aff[e] = (float)(1.0 / (1.0 + exp(-lg)));
    }
    int i1 = 0;
    for (int e = 1; e < NEXP; ++e) if (aff[e] > aff[i1]) i1 = e;
    int i2 = -1;
    for (int e = 0; e < NEXP; ++e) {
      if (e == i1) continue;
      if (i2 < 0 || aff[e] > aff[i2]) i2 = e;
    }
#pragma unroll
    for (int e = 0; e < NEXP; ++e) {
      u64 key = (u64)(0xFFFFFFFFu - (unsigned)t);
      if (e == i1 || e == i2) key |= ((u64)__float_as_uint(aff[e])) << 32;
      keys[(long)e * TOKS + t] = key;
    }
  }
}

// ---------------- transpose fp32 [R][C] -> bf16 [C][R], 64x64 tiles, vectorized ----------------
// PERM: orig col c -> out row ((c&1023)>>4)*32 + (c>>10)*16 + (c&15)
template <bool PERM>
__global__ __launch_bounds__(256) void k_transpose64(
    const float* __restrict__ in0, const float* __restrict__ inr,
    unsigned short* __restrict__ out, int R, int C) {
  __shared__ unsigned short t[64][68];
  int z = blockIdx.z;
  const float* in = (z == 0) ? in0 : (inr + (long)(z - 1) * R * C);
  unsigned short* o = out + (long)z * R * C;
  const int c0 = blockIdx.x * 64;
  const int r0 = blockIdx.y * 64;
  const int tid = threadIdx.x;
  const int lrow = tid >> 4;        // 0..15
  const int lc4 = (tid & 15) * 4;   // 0..60
#pragma unroll
  for (int i = 0; i < 4; ++i) {
    int r = lrow + i * 16;
    float4 v = *(const float4*)&in[(long)(r0 + r) * C + c0 + lc4];
    t[r][lc4 + 0] = f2bf(v.x);
    t[r][lc4 + 1] = f2bf(v.y);
    t[r][lc4 + 2] = f2bf(v.z);
    t[r][lc4 + 3] = f2bf(v.w);
  }
  __syncthreads();
  const int lc = tid >> 2;  // out row-local 0..63
  const int c = c0 + lc;
  const long orow = PERM ? (long)(((c & 1023) >> 4) * 32 + ((c >> 10) << 4) + (c & 15))
                         : (long)c;
#pragma unroll
  for (int j = 0; j < 2; ++j) {
    int rloc = ((tid & 3) + j * 4) * 8;
    ushort8_t o8;
#pragma unroll
    for (int q = 0; q < 8; ++q) o8[q] = t[rloc + q][lc];
    *(ushort8_t*)&o[orow * R + r0 + rloc] = o8;
  }
}

// ---------------- per-expert radix-select of top-CAP keys + inverse map ----------------
__global__ __launch_bounds__(1024) void k_select(
    const u64* __restrict__ keys, int* __restrict__ sel,
    float* __restrict__ selw, unsigned* __restrict__ cnt,
    int* __restrict__ inv) {
  __shared__ unsigned hist[256];
  __shared__ u64 s_prefix;
  __shared__ unsigned s_k;
  __shared__ unsigned s_cnt;
  const int e = blockIdx.x;
  const u64* kk = keys + (long)e * TOKS;
  const int tid = threadIdx.x;
  if (tid == 0) { s_prefix = 0; s_k = CAP; s_cnt = 0; }
  __syncthreads();
  for (int shift = 56; shift >= 0; shift -= 8) {
    if (tid < 256) hist[tid] = 0;
    __syncthreads();
    u64 pref = s_prefix;
    for (int i = tid; i < TOKS; i += 1024) {
      u64 key = kk[i];
      bool match = (shift == 56) || ((key >> (shift + 8)) == pref);
      if (match) atomicAdd(&hist[(unsigned)(key >> shift) & 255u], 1u);
    }
    __syncthreads();
    if (tid == 0) {
      unsigned k = s_k, cum = 0;
      for (int b = 255; b >= 0; --b) {
        unsigned c = hist[b];
        if (cum + c >= k) {
          s_prefix = (s_prefix << 8) | (unsigned)b;
          s_k = k - cum;
          break;
        }
        cum += c;
      }
    }
    __syncthreads();
  }
  const u64 T = s_prefix;  // exact CAP-th largest key
  for (int i = tid; i < TOKS; i += 1024) {
    u64 key = kk[i];
    if (key >= T) {
      unsigned p = atomicAdd(&s_cnt, 1u);
      int tok = (int)(0xFFFFFFFFu - (unsigned)(key & 0xFFFFFFFFull));
      unsigned vb = (unsigned)(key >> 32);
      sel[e * CAPP + p] = tok;
      selw[e * CAPP + p] = vb ? __uint_as_float(vb) : 0.0f;
      if (vb) {
        unsigned pos = atomicAdd(&cnt[tok], 1u);
        inv[tok * 2 + pos] = e * CAPP + (int)p;
      }
    }
  }
  for (int i = CAP + tid; i < CAPP; i += 1024) {
    sel[e * CAPP + i] = 0;
    selw[e * CAPP + i] = 0.0f;
  }
}

// ---------------- combine: out[tok] += sum over inv of routed rows (bf16) ----------------
__global__ __launch_bounds__(256) void k_combine(
    float* __restrict__ out, const unsigned short* __restrict__ rout,
    const int* __restrict__ inv, const unsigned* __restrict__ cnt) {
  const int tok = blockIdx.x;
  const unsigned c = cnt[tok];
  if (c == 0) return;
  int i0 = inv[tok * 2];
  int i1 = (c > 1) ? inv[tok * 2 + 1] : -1;
  if (c > 1 && i1 < i0) { int t = i0; i0 = i1; i1 = t; }  // canonical order
  const int col = threadIdx.x * 8;
  float* o = out + (long)tok * DMODEL + col;
  float4 v0 = *(float4*)o;
  float4 v1 = *(float4*)(o + 4);
  ushort8_t r0 = *(const ushort8_t*)&rout[(long)i0 * DMODEL + col];
  v0.x += bf2f(r0[0]); v0.y += bf2f(r0[1]); v0.z += bf2f(r0[2]); v0.w += bf2f(r0[3]);
  v1.x += bf2f(r0[4]); v1.y += bf2f(r0[5]); v1.z += bf2f(r0[6]); v1.w += bf2f(r0[7]);
  if (c > 1) {
    ushort8_t r1 = *(const ushort8_t*)&rout[(long)i1 * DMODEL + col];
    v0.x += bf2f(r1[0]); v0.y += bf2f(r1[1]); v0.z += bf2f(r1[2]); v0.w += bf2f(r1[3]);
    v1.x += bf2f(r1[4]); v1.y += bf2f(r1[5]); v1.z += bf2f(r1[6]); v1.w += bf2f(r1[7]);
  }
  *(float4*)o = v0;
  *(float4*)(o + 4) = v1;
}

// ---------------- fused 256x128 2-phase GEMM over unified (shared+routed) rows ----------------
// WHICH=1: xb[gathered] @ w1t[zw]^T -> SwiGLU -> a_all; WHICH=2: a_all @ w2t[zw]^T
//          -> shared: fp32 out; routed: weighted bf16 r_out.
// Grid 1072 = 8 XCDs x (2 col-tiles x 67 row-tiles). Each XCD walks ALL rows for its
// 2 cols (row-fastest) -> B col-panel (<=1MB/XCD) pinned in L2; A streams via L3.
// 512 thr = 8 waves (4M x 2N), per-wave 64x64, BK=32, 2x24KB LDS dbuf.
template <int WHICH>
__global__ __launch_bounds__(512, 4) void k_ffn(
    const unsigned short* __restrict__ Abase,
    const unsigned short* __restrict__ Wbase,
    unsigned short* __restrict__ a_all, float* __restrict__ out,
    unsigned short* __restrict__ r_out,
    const int* __restrict__ sel, const float* __restrict__ selw) {
  constexpr int K = (WHICH == 1) ? DMODEL : FD;
  constexpr int N = (WHICH == 1) ? 2 * FD : DMODEL;
  constexpr int nk = K >> 5;
  constexpr int ASH = 256 * 32;  // A shorts per buf (16KB)
  __shared__ unsigned short lds[2][ASH + 128 * 32];  // +B 8KB => 24KB/buf
  const int tid = threadIdx.x;
  const int w = tid >> 6;
  const int lane = tid & 63;

  // ---- XCD col-panel pinning: lin%8 = XCD; per-XCD 134 = 2 cols x 67 rows, row-fastest
  int lin = blockIdx.x + ((int)blockIdx.y << 4);  // 0..1071
  int xcd = lin & 7;
  int tt = lin >> 3;              // 0..133
  int colh = (tt >= URT256) ? 1 : 0;
  int by_u = tt - colh * URT256;  // 0..66
  int bx = xcd * 2 + colh;        // 0..15

  int e, zw, m0l;
  if (by_u < 32) { e = -1; zw = 0; m0l = by_u << 8; }
  else { int q = by_u - 32; e = q / 5; zw = e + 1; m0l = (q % 5) << 8; }
  const long crow0_u = (e < 0) ? (long)m0l : (8192 + (long)e * CAPP + m0l);
  const long n0 = (long)bx * 128;
  const unsigned short* Bm = Wbase + (long)zw * N * K;

  // ---- staging source pointers (pre-swizzled col; involution f(r) = (r>>1)&3) ----
  const unsigned short* aSrc[2];
  const unsigned short* bSrc;
#pragma unroll
  for (int j = 0; j < 2; ++j) {
    int r = w * 32 + j * 16 + (lane >> 2);  // 0..255
    int q = (lane & 3) ^ ((r >> 1) & 3);
    long arow;
    if (WHICH == 1)
      arow = (e < 0) ? (long)(m0l + r) : (long)sel[e * CAPP + m0l + r];
    else
      arow = crow0_u + r;
    aSrc[j] = Abase + arow * (long)K + q * 8;
  }
  {
    int r = w * 16 + (lane >> 2);  // 0..127
    int q = (lane & 3) ^ ((r >> 1) & 3);
    bSrc = Bm + (n0 + r) * (long)K + q * 8;
  }
  const int dstA0 = (w * 128 + lane) * 8;        // + j*64*8 shorts
  const int dstB0 = ASH + (w * 64 + lane) * 8;

  auto STAGE = [&](int buf, int kt) {
    const long ko = (long)kt * 32;
    gload_lds16(aSrc[0] + ko, &lds[buf][dstA0]);
    gload_lds16(aSrc[1] + ko, &lds[buf][dstA0 + 512]);
    gload_lds16(bSrc + ko, &lds[buf][dstB0]);
  };

  const int wr = w >> 1, wc = w & 1;
  const int lr = lane & 15, kq = lane >> 4;
  const int slot = (kq ^ ((lr >> 1) & 3)) * 8;
  const int aRow = wr * 64 + lr;
  const int bRow = wc * 64 + lr;

  STAGE(0, 0);
  asm volatile("s_waitcnt vmcnt(0)" ::: "memory");
  __builtin_amdgcn_sched_barrier(0);
  __builtin_amdgcn_s_barrier();
  __builtin_amdgcn_sched_barrier(0);

  f32x4 acc[4][4] = {};
  int cur = 0;

#pragma unroll 1
  for (int kt = 0; kt < nk; ++kt) {
    if (kt + 1 < nk) STAGE(cur ^ 1, kt + 1);
    const unsigned short* aSeg = &lds[cur][0];
    const unsigned short* bSeg = &lds[cur][ASH];
    bf16x8 af[4], bf[4];
#pragma unroll
    for (int m = 0; m < 4; ++m)
      af[m] = *(const bf16x8*)&aSeg[(aRow + m * 16) * 32 + slot];
#pragma unroll
    for (int n = 0; n < 4; ++n)
      bf[n] = *(const bf16x8*)&bSeg[(bRow + n * 16) * 32 + slot];
    asm volatile("s_waitcnt lgkmcnt(0)" ::: "memory");
    __builtin_amdgcn_sched_barrier(0);
    __builtin_amdgcn_s_setprio(1);
#pragma unroll
    for (int m = 0; m < 4; ++m)
#pragma unroll
      for (int n = 0; n < 4; ++n)
        acc[m][n] = MFMA16(af[m], bf[n], acc[m][n]);
    __builtin_amdgcn_s_setprio(0);
    asm volatile("s_waitcnt vmcnt(0)" ::: "memory");
    __builtin_amdgcn_sched_barrier(0);
    __builtin_amdgcn_s_barrier();
    __builtin_amdgcn_sched_barrier(0);
    cur ^= 1;
  }

  // ---- epilogue ----
  const int r0q = (lane >> 4) * 4;
  const int cc = lane & 15;

  if (WHICH == 1) {  // SwiGLU fused store into a_all [., FD]
    const long gcol0 = (n0 >> 1) + wc * 32;
#pragma unroll
    for (int m = 0; m < 4; ++m)
#pragma unroll
      for (int rj = 0; rj < 4; ++rj) {
        long row = crow0_u + wr * 64 + m * 16 + r0q + rj;
#pragma unroll
        for (int q2 = 0; q2 < 2; ++q2) {
          float x1v = acc[m][2 * q2][rj];
          float x2v = acc[m][2 * q2 + 1][rj];
          float s = x2v / (1.0f + __expf(-x2v));
          a_all[row * FD + gcol0 + q2 * 16 + cc] = f2bf(x1v * s);
        }
      }
  } else {
    const long ccol0 = n0 + wc * 64;
    if (e < 0) {  // shared -> fp32 out (full overwrite)
#pragma unroll
      for (int m = 0; m < 4; ++m)
#pragma unroll
        for (int rj = 0; rj < 4; ++rj) {
          long row = m0l + wr * 64 + m * 16 + r0q + rj;
#pragma unroll
          for (int n = 0; n < 4; ++n)
            out[row * DMODEL + ccol0 + n * 16 + cc] = acc[m][n][rj];
        }
    } else {  // routed -> weighted bf16 dense r_out
#pragma unroll
      for (int m = 0; m < 4; ++m)
#pragma unroll
        for (int rj = 0; rj < 4; ++rj) {
          int lrow = m0l + wr * 64 + m * 16 + r0q + rj;
          float wgt = selw[e * CAPP + lrow];
          unsigned short* C = r_out + ((long)e * CAPP + lrow) * DMODEL;
#pragma unroll
          for (int n = 0; n < 4; ++n)
            C[ccol0 + n * 16 + cc] = f2bf(acc[m][n][rj] * wgt);
        }
    }
  }
}

extern "C" void kernel_launch(void* const* d_in, const int* in_sizes, int n_in,
                              void* d_out, int out_size, void* d_ws,
                              size_t ws_size, hipStream_t stream) {
  (void)in_sizes; (void)n_in; (void)out_size; (void)ws_size;
  const float* x = (const float*)d_in[0];
  const float* gw = (const float*)d_in[1];
  const float* eb = (const float*)d_in[2];
  const float* sw1 = (const float*)d_in[3];
  const float* sw2 = (const float*)d_in[4];
  const float* rw1 = (const float*)d_in[5];
  const float* rw2 = (const float*)d_in[6];
  float* out = (float*)d_out;

  char* ws = (char*)d_ws;
  size_t off = 0;
  auto alloc = [&](size_t bytes) {
    size_t o = off;
    off += (bytes + 255) & ~(size_t)255;
    return o;
  };
  unsigned short* xb    = (unsigned short*)(ws + alloc((size_t)TOKS * DMODEL * 2));
  unsigned short* w1t   = (unsigned short*)(ws + alloc((size_t)8 * DMODEL * (2 * FD) * 2));
  unsigned short* w2t   = (unsigned short*)(ws + alloc((size_t)8 * DMODEL * FD * 2));
  unsigned short* a_all = (unsigned short*)(ws + alloc((size_t)(TOKS + NEXP * CAPP) * FD * 2));
  unsigned short* r_out = (unsigned short*)(ws + alloc((size_t)NEXP * CAPP * DMODEL * 2));
  u64* keys = (u64*)(ws + alloc((size_t)NEXP * TOKS * 8));
  int* sel  = (int*)(ws + alloc((size_t)NEXP * CAPP * 4));
  float* selw = (float*)(ws + alloc((size_t)NEXP * CAPP * 4));
  unsigned* cnt = (unsigned*)(ws + alloc((size_t)TOKS * 4));
  int* inv = (int*)(ws + alloc((size_t)TOKS * 2 * 4));

  // 1. fused convert + gating (single read of x)
  k_conv_gate<<<TOKS, 256, 0, stream>>>(x, gw, eb, xb, keys);
  // 2./3. weight transposes (vectorized 64x64; w1 with x1/x2 16-block interleave)
  k_transpose64<true><<<dim3(32, 32, 8), 256, 0, stream>>>(sw1, rw1, w1t, DMODEL, 2 * FD);
  k_transpose64<false><<<dim3(32, 16, 8), 256, 0, stream>>>(sw2, rw2, w2t, FD, DMODEL);
  // 4. per-expert selection (radix-select) + inverse map
  hipMemsetAsync(cnt, 0, (size_t)TOKS * 4, stream);
  k_select<<<NEXP, 1024, 0, stream>>>(keys, sel, selw, cnt, inv);
  // 5. fused GEMM1 (shared + routed) + SwiGLU -> a_all
  k_ffn<1><<<dim3(16, URT256), 512, 0, stream>>>(xb, w1t, a_all, nullptr, nullptr,
                                                 sel, nullptr);
  // 6. fused GEMM2 -> out (shared, fp32) / r_out (routed, weighted bf16)
  k_ffn<2><<<dim3(16, URT256), 512, 0, stream>>>(a_all, w2t, nullptr, out, r_out,
                                                 nullptr, selw);
  // 7. combine: out[tok] += sum of routed rows
  k_combine<<<TOKS, 256, 0, stream>>>(out, r_out, inv, cnt);
}

// Round 9
// 504.313 us; speedup vs baseline: 1.0331x; 1.0331x over previous
//
#include <hip/hip_runtime.h>
#include <hip/hip_bf16.h>

typedef unsigned long long u64;
typedef __bf16 bf16x8 __attribute__((ext_vector_type(8)));
typedef float f32x4 __attribute__((ext_vector_type(4)));
typedef unsigned short ushort8_t __attribute__((ext_vector_type(8)));

#define TOKS 8192
#define DMODEL 2048
#define FD 1024
#define NEXP 7
#define CAP 1170
#define CAPP 1280
#define URT256 67  // 32 shared + 7*5 routed row-tiles of 256

#define MFMA16(a, b, c) __builtin_amdgcn_mfma_f32_16x16x32_bf16(a, b, c, 0, 0, 0)

__device__ __forceinline__ unsigned short f2bf(float f) {
  __hip_bfloat16 b = __float2bfloat16(f);
  return __builtin_bit_cast(unsigned short, b);
}
__device__ __forceinline__ float bf2f(unsigned short u) {
  __hip_bfloat16 b = __builtin_bit_cast(__hip_bfloat16, u);
  return __bfloat162float(b);
}
__device__ __forceinline__ void gload_lds16(const void* g, void* l) {
  __builtin_amdgcn_global_load_lds(
      (const __attribute__((address_space(1))) void*)g,
      (__attribute__((address_space(3))) void*)l, 16, 0, 0);
}

// ---------------- fused x fp32->bf16 convert + gating (1 block = 1 token) ----------------
__global__ __launch_bounds__(256) void k_conv_gate(
    const float* __restrict__ x, const float* __restrict__ gw,
    const float* __restrict__ bias, unsigned short* __restrict__ xb,
    u64* __restrict__ keys) {
  const int t = blockIdx.x;
  const int tid = threadIdx.x;
  const int lane = tid & 63, wv = tid >> 6;
  const float* xr = x + (long)t * DMODEL;
  const int i0 = tid * 8;
  float4 v0 = *(const float4*)&xr[i0];
  float4 v1 = *(const float4*)&xr[i0 + 4];
  float xv[8] = {v0.x, v0.y, v0.z, v0.w, v1.x, v1.y, v1.z, v1.w};
  ushort8_t o;
#pragma unroll
  for (int j = 0; j < 8; ++j) o[j] = f2bf(xv[j]);
  *(ushort8_t*)&xb[(long)t * DMODEL + i0] = o;
  double acc[NEXP];
#pragma unroll
  for (int e = 0; e < NEXP; ++e) acc[e] = 0.0;
#pragma unroll
  for (int j = 0; j < 8; ++j) {
    const float* g = gw + (long)(i0 + j) * NEXP;
    double xd = (double)xv[j];
#pragma unroll
    for (int e = 0; e < NEXP; ++e) acc[e] += xd * (double)g[e];
  }
#pragma unroll
  for (int e = 0; e < NEXP; ++e)
    for (int off = 32; off > 0; off >>= 1)
      acc[e] += __shfl_down(acc[e], off, 64);
  __shared__ double red[4][NEXP];
  if (lane == 0)
#pragma unroll
    for (int e = 0; e < NEXP; ++e) red[wv][e] = acc[e];
  __syncthreads();
  if (tid == 0) {
    float aff[NEXP];
#pragma unroll
    for (int e = 0; e < NEXP; ++e) {
      double lg = red[0][e] + red[1][e] + red[2][e] + red[3][e] + (double)bias[e];
      aff[e] = (float)(1.0 / (1.0 + exp(-lg)));
    }
    int i1 = 0;
    for (int e = 1; e < NEXP; ++e) if (aff[e] > aff[i1]) i1 = e;
    int i2 = -1;
    for (int e = 0; e < NEXP; ++e) {
      if (e == i1) continue;
      if (i2 < 0 || aff[e] > aff[i2]) i2 = e;
    }
#pragma unroll
    for (int e = 0; e < NEXP; ++e) {
      u64 key = (u64)(0xFFFFFFFFu - (unsigned)t);
      if (e == i1 || e == i2) key |= ((u64)__float_as_uint(aff[e])) << 32;
      keys[(long)e * TOKS + t] = key;
    }
  }
}

// ---------------- transpose fp32 [R][C] -> bf16 [C][R], batched z (R7-proven) ----------------
// PERM: orig col c -> row ((c&1023)>>4)*32 + (c>>10)*16 + (c&15)  (x1/x2 16-block interleave)
template <bool PERM>
__global__ void k_transpose_bf16(const float* __restrict__ in0,
                                 const float* __restrict__ inr,
                                 unsigned short* __restrict__ out,
                                 int R, int C) {
  __shared__ float tile[32][33];
  int z = blockIdx.z;
  const float* in = (z == 0) ? in0 : (inr + (long)(z - 1) * R * C);
  unsigned short* o = out + (long)z * R * C;
  int c0 = blockIdx.x * 32;
  int r0 = blockIdx.y * 32;
  int tx = threadIdx.x, ty = threadIdx.y; // (32,8)
#pragma unroll
  for (int k = 0; k < 4; ++k)
    tile[ty + 8 * k][tx] = in[(long)(r0 + ty + 8 * k) * C + c0 + tx];
  __syncthreads();
#pragma unroll
  for (int k = 0; k < 4; ++k) {
    int c = c0 + ty + 8 * k;
    long orow = PERM ? (long)(((c & 1023) >> 4) * 32 + ((c >> 10) << 4) + (c & 15))
                     : (long)c;
    o[orow * R + r0 + tx] = f2bf(tile[tx][ty + 8 * k]);
  }
}

// ---------------- per-expert radix-select of top-CAP keys + inverse map ----------------
__global__ __launch_bounds__(1024) void k_select(
    const u64* __restrict__ keys, int* __restrict__ sel,
    float* __restrict__ selw, unsigned* __restrict__ cnt,
    int* __restrict__ inv) {
  __shared__ unsigned hist[256];
  __shared__ u64 s_prefix;
  __shared__ unsigned s_k;
  __shared__ unsigned s_cnt;
  const int e = blockIdx.x;
  const u64* kk = keys + (long)e * TOKS;
  const int tid = threadIdx.x;
  if (tid == 0) { s_prefix = 0; s_k = CAP; s_cnt = 0; }
  __syncthreads();
  for (int shift = 56; shift >= 0; shift -= 8) {
    if (tid < 256) hist[tid] = 0;
    __syncthreads();
    u64 pref = s_prefix;
    for (int i = tid; i < TOKS; i += 1024) {
      u64 key = kk[i];
      bool match = (shift == 56) || ((key >> (shift + 8)) == pref);
      if (match) atomicAdd(&hist[(unsigned)(key >> shift) & 255u], 1u);
    }
    __syncthreads();
    if (tid == 0) {
      unsigned k = s_k, cum = 0;
      for (int b = 255; b >= 0; --b) {
        unsigned c = hist[b];
        if (cum + c >= k) {
          s_prefix = (s_prefix << 8) | (unsigned)b;
          s_k = k - cum;
          break;
        }
        cum += c;
      }
    }
    __syncthreads();
  }
  const u64 T = s_prefix;  // exact CAP-th largest key
  for (int i = tid; i < TOKS; i += 1024) {
    u64 key = kk[i];
    if (key >= T) {
      unsigned p = atomicAdd(&s_cnt, 1u);
      int tok = (int)(0xFFFFFFFFu - (unsigned)(key & 0xFFFFFFFFull));
      unsigned vb = (unsigned)(key >> 32);
      sel[e * CAPP + p] = tok;
      selw[e * CAPP + p] = vb ? __uint_as_float(vb) : 0.0f;
      if (vb) {
        unsigned pos = atomicAdd(&cnt[tok], 1u);
        inv[tok * 2 + pos] = e * CAPP + (int)p;
      }
    }
  }
  for (int i = CAP + tid; i < CAPP; i += 1024) {
    sel[e * CAPP + i] = 0;
    selw[e * CAPP + i] = 0.0f;
  }
}

// ---------------- combine: out[tok] += sum over inv of routed rows (bf16) ----------------
__global__ __launch_bounds__(256) void k_combine(
    float* __restrict__ out, const unsigned short* __restrict__ rout,
    const int* __restrict__ inv, const unsigned* __restrict__ cnt) {
  const int tok = blockIdx.x;
  const unsigned c = cnt[tok];
  if (c == 0) return;
  int i0 = inv[tok * 2];
  int i1 = (c > 1) ? inv[tok * 2 + 1] : -1;
  if (c > 1 && i1 < i0) { int t = i0; i0 = i1; i1 = t; }  // canonical order
  const int col = threadIdx.x * 8;
  float* o = out + (long)tok * DMODEL + col;
  float4 v0 = *(float4*)o;
  float4 v1 = *(float4*)(o + 4);
  ushort8_t r0 = *(const ushort8_t*)&rout[(long)i0 * DMODEL + col];
  v0.x += bf2f(r0[0]); v0.y += bf2f(r0[1]); v0.z += bf2f(r0[2]); v0.w += bf2f(r0[3]);
  v1.x += bf2f(r0[4]); v1.y += bf2f(r0[5]); v1.z += bf2f(r0[6]); v1.w += bf2f(r0[7]);
  if (c > 1) {
    ushort8_t r1 = *(const ushort8_t*)&rout[(long)i1 * DMODEL + col];
    v0.x += bf2f(r1[0]); v0.y += bf2f(r1[1]); v0.z += bf2f(r1[2]); v0.w += bf2f(r1[3]);
    v1.x += bf2f(r1[4]); v1.y += bf2f(r1[5]); v1.z += bf2f(r1[6]); v1.w += bf2f(r1[7]);
  }
  *(float4*)o = v0;
  *(float4*)(o + 4) = v1;
}

// ---------------- fused 256x256 8-phase GEMM (m201 skeleton, corrected port) ----------------
// 512 thr = 8 waves (2M x 4N), per-wave 128x64, BK=64, 2 dbuf x {A0,A1,B0,B1} x 16KB = 128KB.
// Per phase: ds_read(this phase) BEFORE barrier (latency hides under barrier wait);
// stages: ph0 B0(T+1), ph1 B1(T+1), ph3 A0+A1(T+2) then vmcnt(4) (retires exactly tile T+1's
// 8 loads per FIFO algebra) -> barrier -> lgkmcnt(0) -> setprio(1) 16 MFMA setprio(0) -> barrier.
// Grid (8 cols, 67 unified rows): blockIdx.x = XCD -> B col-panel (<=1MB) L2-pinned.
// WHICH=1: xb[gathered] @ w1t^T -> SwiGLU -> a_all; WHICH=2: a_all @ w2t^T -> out / r_out.
template <int WHICH>
__global__ __launch_bounds__(512, 2) void k_ffn8(
    const unsigned short* __restrict__ Abase,
    const unsigned short* __restrict__ Wbase,
    unsigned short* __restrict__ a_all, float* __restrict__ out,
    unsigned short* __restrict__ r_out,
    const int* __restrict__ sel, const float* __restrict__ selw) {
  constexpr int K = (WHICH == 1) ? DMODEL : FD;
  constexpr int N = 2048;
  constexpr int nk = K >> 6;
  extern __shared__ unsigned short lds[];  // 8 segs x 8192 shorts
  const int tid = threadIdx.x;
  const int w = tid >> 6;
  const int lane = tid & 63;

  const int bx = blockIdx.x;    // 0..7 == XCD (round-robin dispatch)
  const int by_u = blockIdx.y;  // 0..66 unified row tile

  int e, zw, m0l;
  if (by_u < 32) { e = -1; zw = 0; m0l = by_u << 8; }
  else { int q = by_u - 32; e = q / 5; zw = e + 1; m0l = (q % 5) << 8; }
  const long crow0_u = (e < 0) ? (long)m0l : (8192 + (long)e * CAPP + m0l);
  const long n0 = (long)bx * 256;
  const unsigned short* Bm = Wbase + (long)zw * N * K;

  const int wr = w >> 2;  // 0..1 M half
  const int wc = w & 3;   // 0..3 N quarter
  const int lr = lane & 15;
  const int kq = lane >> 4;

  // ---- staging source pointers (pre-swizzled global col; LDS dest linear) ----
  const unsigned short* aP[2][2];
  const unsigned short* bP[2][2];
  int dstOff[2];
#pragma unroll
  for (int j = 0; j < 2; ++j) {
    int L = w * 128 + j * 64 + lane;          // 0..1023 linear slot in segment
    int r = L >> 3;                           // row 0..127
    int cEl = ((L & 7) * 8) ^ ((r & 7) * 8);  // swizzled col (elements)
    dstOff[j] = (w * 2 + j) * 512;
#pragma unroll
    for (int h = 0; h < 2; ++h) {
      long ar;
      if (WHICH == 1)
        ar = (e < 0) ? (long)(m0l + h * 128 + r)
                     : (long)sel[e * CAPP + m0l + h * 128 + r];
      else
        ar = crow0_u + h * 128 + r;
      aP[h][j] = Abase + ar * (long)K + cEl;
      bP[h][j] = Bm + (n0 + h * 128 + r) * (long)K + cEl;
    }
  }

  auto STAGE = [&](int seg, int d, int ts) {
    unsigned short* base = lds + ((d << 2) + seg) * 8192;
    const unsigned short *p0, *p1;
    if (seg < 2) { p0 = aP[seg][0]; p1 = aP[seg][1]; }
    else         { p0 = bP[seg - 2][0]; p1 = bP[seg - 2][1]; }
    long ko = (long)ts * 64;
    gload_lds16(p0 + ko, base + dstOff[0]);
    gload_lds16(p1 + ko, base + dstOff[1]);
  };

  // ---- swizzled LDS read offsets ----
  const int aSegT = wr;
  const int bSegT = 2 + (wc >> 1);
  const int colSw0 = (kq * 8) ^ ((lr & 7) * 8);
  const int colSw1 = (32 + kq * 8) ^ ((lr & 7) * 8);
  const int bRow = (wc & 1) * 64 + lr;

  // prologue: A(0), B(0), A(1) -> 12 loads; vmcnt(4) confirms tile 0 (8 oldest)
  STAGE(0, 0, 0); STAGE(1, 0, 0); STAGE(2, 0, 0); STAGE(3, 0, 0);
  if (nk > 1) { STAGE(0, 1, 1); STAGE(1, 1, 1); }
  else        { STAGE(0, 1, 0); STAGE(1, 1, 0); }
  asm volatile("s_waitcnt vmcnt(4)" ::: "memory");
  __builtin_amdgcn_sched_barrier(0);
  __builtin_amdgcn_s_barrier();
  __builtin_amdgcn_sched_barrier(0);

  f32x4 acc[8][4] = {};

#pragma unroll 1
  for (int T = 0; T < nk; ++T) {
    const int d = T & 1, dn = d ^ 1;
    int t1 = T + 1; if (t1 >= nk) t1 -= nk;  // tail: dummy restage (count-preserving)
    int t2 = T + 2; if (t2 >= nk) t2 -= nk;
    const unsigned short* aSeg = lds + ((d << 2) + aSegT) * 8192;
    const unsigned short* bSeg = lds + ((d << 2) + bSegT) * 8192;
    bf16x8 af[8], b0, b1;

    // ---------- phase 0: reads(A kk0, B n0 n1 kk0) ; stage B0(T+1) ; barrier ----------
#pragma unroll
    for (int m = 0; m < 8; ++m)
      af[m] = *(const bf16x8*)&aSeg[(m * 16 + lr) * 64 + colSw0];
    b0 = *(const bf16x8*)&bSeg[(bRow + 0) * 64 + colSw0];
    b1 = *(const bf16x8*)&bSeg[(bRow + 16) * 64 + colSw0];
    __builtin_amdgcn_sched_barrier(0);
    STAGE(2, dn, t1);
    __builtin_amdgcn_sched_barrier(0);
    __builtin_amdgcn_s_barrier();
    asm volatile("s_waitcnt lgkmcnt(0)" ::: "memory");
    __builtin_amdgcn_sched_barrier(0);
    __builtin_amdgcn_s_setprio(1);
#pragma unroll
    for (int m = 0; m < 8; ++m) {
      acc[m][0] = MFMA16(af[m], b0, acc[m][0]);
      acc[m][1] = MFMA16(af[m], b1, acc[m][1]);
    }
    __builtin_amdgcn_s_setprio(0);
    __builtin_amdgcn_sched_barrier(0);
    __builtin_amdgcn_s_barrier();
    __builtin_amdgcn_sched_barrier(0);

    // ---------- phase 1: reads(B n2 n3 kk0) ; stage B1(T+1) ; barrier ----------
    b0 = *(const bf16x8*)&bSeg[(bRow + 32) * 64 + colSw0];
    b1 = *(const bf16x8*)&bSeg[(bRow + 48) * 64 + colSw0];
    __builtin_amdgcn_sched_barrier(0);
    STAGE(3, dn, t1);
    __builtin_amdgcn_sched_barrier(0);
    __builtin_amdgcn_s_barrier();
    asm volatile("s_waitcnt lgkmcnt(0)" ::: "memory");
    __builtin_amdgcn_sched_barrier(0);
    __builtin_amdgcn_s_setprio(1);
#pragma unroll
    for (int m = 0; m < 8; ++m) {
      acc[m][2] = MFMA16(af[m], b0, acc[m][2]);
      acc[m][3] = MFMA16(af[m], b1, acc[m][3]);
    }
    __builtin_amdgcn_s_setprio(0);
    __builtin_amdgcn_sched_barrier(0);
    __builtin_amdgcn_s_barrier();
    __builtin_amdgcn_sched_barrier(0);

    // ---------- phase 2: reads(A kk1, B n0 n1 kk1) ; no stage ; barrier ----------
#pragma unroll
    for (int m = 0; m < 8; ++m)
      af[m] = *(const bf16x8*)&aSeg[(m * 16 + lr) * 64 + colSw1];
    b0 = *(const bf16x8*)&bSeg[(bRow + 0) * 64 + colSw1];
    b1 = *(const bf16x8*)&bSeg[(bRow + 16) * 64 + colSw1];
    __builtin_amdgcn_sched_barrier(0);
    __builtin_amdgcn_s_barrier();
    asm volatile("s_waitcnt lgkmcnt(0)" ::: "memory");
    __builtin_amdgcn_sched_barrier(0);
    __builtin_amdgcn_s_setprio(1);
#pragma unroll
    for (int m = 0; m < 8; ++m) {
      acc[m][0] = MFMA16(af[m], b0, acc[m][0]);
      acc[m][1] = MFMA16(af[m], b1, acc[m][1]);
    }
    __builtin_amdgcn_s_setprio(0);
    __builtin_amdgcn_sched_barrier(0);
    __builtin_amdgcn_s_barrier();
    __builtin_amdgcn_sched_barrier(0);

    // ---------- phase 3: reads(B n2 n3 kk1) ; stage A0 A1(T+2) ; vmcnt(4) ; barrier ----------
    b0 = *(const bf16x8*)&bSeg[(bRow + 32) * 64 + colSw1];
    b1 = *(const bf16x8*)&bSeg[(bRow + 48) * 64 + colSw1];
    __builtin_amdgcn_sched_barrier(0);
    STAGE(0, d, t2);
    STAGE(1, d, t2);
    asm volatile("s_waitcnt vmcnt(4)" ::: "memory");
    __builtin_amdgcn_sched_barrier(0);
    __builtin_amdgcn_s_barrier();
    asm volatile("s_waitcnt lgkmcnt(0)" ::: "memory");
    __builtin_amdgcn_sched_barrier(0);
    __builtin_amdgcn_s_setprio(1);
#pragma unroll
    for (int m = 0; m < 8; ++m) {
      acc[m][2] = MFMA16(af[m], b0, acc[m][2]);
      acc[m][3] = MFMA16(af[m], b1, acc[m][3]);
    }
    __builtin_amdgcn_s_setprio(0);
    __builtin_amdgcn_sched_barrier(0);
    __builtin_amdgcn_s_barrier();
    __builtin_amdgcn_sched_barrier(0);
  }
  asm volatile("s_waitcnt vmcnt(0)" ::: "memory");

  // ---- epilogue ----
  const int r0q = (lane >> 4) * 4;
  const int cc = lane & 15;

  if (WHICH == 1) {  // SwiGLU fused store into a_all [., FD]
    const long gcol0 = (n0 >> 1) + wc * 32;
#pragma unroll
    for (int m = 0; m < 8; ++m)
#pragma unroll
      for (int rj = 0; rj < 4; ++rj) {
        long row = crow0_u + wr * 128 + m * 16 + r0q + rj;
#pragma unroll
        for (int q2 = 0; q2 < 2; ++q2) {
          float x1v = acc[m][2 * q2][rj];
          float x2v = acc[m][2 * q2 + 1][rj];
          float s = x2v / (1.0f + __expf(-x2v));
          a_all[row * FD + gcol0 + q2 * 16 + cc] = f2bf(x1v * s);
        }
      }
  } else {
    const long ccol0 = n0 + wc * 64;
    if (e < 0) {  // shared -> fp32 out (full overwrite)
#pragma unroll
      for (int m = 0; m < 8; ++m)
#pragma unroll
        for (int rj = 0; rj < 4; ++rj) {
          long row = m0l + wr * 128 + m * 16 + r0q + rj;
#pragma unroll
          for (int n = 0; n < 4; ++n)
            out[row * DMODEL + ccol0 + n * 16 + cc] = acc[m][n][rj];
        }
    } else {  // routed -> weighted bf16 dense r_out
#pragma unroll
      for (int m = 0; m < 8; ++m)
#pragma unroll
        for (int rj = 0; rj < 4; ++rj) {
          int lrow = m0l + wr * 128 + m * 16 + r0q + rj;
          float wgt = selw[e * CAPP + lrow];
          unsigned short* C = r_out + ((long)e * CAPP + lrow) * DMODEL;
#pragma unroll
          for (int n = 0; n < 4; ++n)
            C[ccol0 + n * 16 + cc] = f2bf(acc[m][n][rj] * wgt);
        }
    }
  }
}

extern "C" void kernel_launch(void* const* d_in, const int* in_sizes, int n_in,
                              void* d_out, int out_size, void* d_ws,
                              size_t ws_size, hipStream_t stream) {
  (void)in_sizes; (void)n_in; (void)out_size; (void)ws_size;
  const float* x = (const float*)d_in[0];
  const float* gw = (const float*)d_in[1];
  const float* eb = (const float*)d_in[2];
  const float* sw1 = (const float*)d_in[3];
  const float* sw2 = (const float*)d_in[4];
  const float* rw1 = (const float*)d_in[5];
  const float* rw2 = (const float*)d_in[6];
  float* out = (float*)d_out;

  char* ws = (char*)d_ws;
  size_t off = 0;
  auto alloc = [&](size_t bytes) {
    size_t o = off;
    off += (bytes + 255) & ~(size_t)255;
    return o;
  };
  unsigned short* xb    = (unsigned short*)(ws + alloc((size_t)TOKS * DMODEL * 2));
  unsigned short* w1t   = (unsigned short*)(ws + alloc((size_t)8 * DMODEL * (2 * FD) * 2));
  unsigned short* w2t   = (unsigned short*)(ws + alloc((size_t)8 * DMODEL * FD * 2));
  unsigned short* a_all = (unsigned short*)(ws + alloc((size_t)(TOKS + NEXP * CAPP) * FD * 2));
  unsigned short* r_out = (unsigned short*)(ws + alloc((size_t)NEXP * CAPP * DMODEL * 2));
  u64* keys = (u64*)(ws + alloc((size_t)NEXP * TOKS * 8));
  int* sel  = (int*)(ws + alloc((size_t)NEXP * CAPP * 4));
  float* selw = (float*)(ws + alloc((size_t)NEXP * CAPP * 4));
  unsigned* cnt = (unsigned*)(ws + alloc((size_t)TOKS * 4));
  int* inv = (int*)(ws + alloc((size_t)TOKS * 2 * 4));

  const size_t LDSB = 131072;  // 8 segments x 16 KiB

  // 1. fused convert + gating (single read of x)
  k_conv_gate<<<TOKS, 256, 0, stream>>>(x, gw, eb, xb, keys);
  // 2./3. weight transposes (R7-proven 32x32; w1 with x1/x2 16-block interleave)
  dim3 tb(32, 8);
  k_transpose_bf16<true><<<dim3(64, 64, 8), tb, 0, stream>>>(sw1, rw1, w1t, DMODEL, 2 * FD);
  k_transpose_bf16<false><<<dim3(64, 32, 8), tb, 0, stream>>>(sw2, rw2, w2t, FD, DMODEL);
  // 4. per-expert selection (radix-select) + inverse map
  hipMemsetAsync(cnt, 0, (size_t)TOKS * 4, stream);
  k_select<<<NEXP, 1024, 0, stream>>>(keys, sel, selw, cnt, inv);
  // 5. fused GEMM1 (shared + routed) + SwiGLU -> a_all   (8-phase, 256^2, B panel/XCD)
  k_ffn8<1><<<dim3(8, URT256), 512, LDSB, stream>>>(xb, w1t, a_all, nullptr,
                                                    nullptr, sel, nullptr);
  // 6. fused GEMM2 -> out (shared, fp32) / r_out (routed, weighted bf16)
  k_ffn8<2><<<dim3(8, URT256), 512, LDSB, stream>>>(a_all, w2t, nullptr, out,
                                                    r_out, nullptr, selw);
  // 7. combine: out[tok] += sum of routed rows
  k_combine<<<TOKS, 256, 0, stream>>>(out, r_out, inv, cnt);
}

// Round 10
// 496.479 us; speedup vs baseline: 1.0494x; 1.0158x over previous
//
#include <hip/hip_runtime.h>
#include <hip/hip_bf16.h>

typedef unsigned long long u64;
typedef __bf16 bf16x8 __attribute__((ext_vector_type(8)));
typedef float f32x4 __attribute__((ext_vector_type(4)));
typedef unsigned short ushort8_t __attribute__((ext_vector_type(8)));

#define TOKS 8192
#define DMODEL 2048
#define FD 1024
#define NEXP 7
#define CAP 1170
#define CAPP 1280
#define URT256 67   // 256-row unified tiles: 32 shared + 7*5 routed
#define URT128 134  // 128-row unified tiles: 64 shared + 7*10 routed

#define MFMA16(a, b, c) __builtin_amdgcn_mfma_f32_16x16x32_bf16(a, b, c, 0, 0, 0)

__device__ __forceinline__ unsigned short f2bf(float f) {
  __hip_bfloat16 b = __float2bfloat16(f);
  return __builtin_bit_cast(unsigned short, b);
}
__device__ __forceinline__ float bf2f(unsigned short u) {
  __hip_bfloat16 b = __builtin_bit_cast(__hip_bfloat16, u);
  return __bfloat162float(b);
}
__device__ __forceinline__ void gload_lds16(const void* g, void* l) {
  __builtin_amdgcn_global_load_lds(
      (const __attribute__((address_space(1))) void*)g,
      (__attribute__((address_space(3))) void*)l, 16, 0, 0);
}

// ---------------- fused x fp32->bf16 convert + gating (1 block = 1 token) ----------------
__global__ __launch_bounds__(256) void k_conv_gate(
    const float* __restrict__ x, const float* __restrict__ gw,
    const float* __restrict__ bias, unsigned short* __restrict__ xb,
    u64* __restrict__ keys) {
  const int t = blockIdx.x;
  const int tid = threadIdx.x;
  const int lane = tid & 63, wv = tid >> 6;
  const float* xr = x + (long)t * DMODEL;
  const int i0 = tid * 8;
  float4 v0 = *(const float4*)&xr[i0];
  float4 v1 = *(const float4*)&xr[i0 + 4];
  float xv[8] = {v0.x, v0.y, v0.z, v0.w, v1.x, v1.y, v1.z, v1.w};
  ushort8_t o;
#pragma unroll
  for (int j = 0; j < 8; ++j) o[j] = f2bf(xv[j]);
  *(ushort8_t*)&xb[(long)t * DMODEL + i0] = o;
  double acc[NEXP];
#pragma unroll
  for (int e = 0; e < NEXP; ++e) acc[e] = 0.0;
#pragma unroll
  for (int j = 0; j < 8; ++j) {
    const float* g = gw + (long)(i0 + j) * NEXP;
    double xd = (double)xv[j];
#pragma unroll
    for (int e = 0; e < NEXP; ++e) acc[e] += xd * (double)g[e];
  }
#pragma unroll
  for (int e = 0; e < NEXP; ++e)
    for (int off = 32; off > 0; off >>= 1)
      acc[e] += __shfl_down(acc[e], off, 64);
  __shared__ double red[4][NEXP];
  if (lane == 0)
#pragma unroll
    for (int e = 0; e < NEXP; ++e) red[wv][e] = acc[e];
  __syncthreads();
  if (tid == 0) {
    float aff[NEXP];
#pragma unroll
    for (int e = 0; e < NEXP; ++e) {
      double lg = red[0][e] + red[1][e] + red[2][e] + red[3][e] + (double)bias[e];
      aff[e] = (float)(1.0 / (1.0 + exp(-lg)));
    }
    int i1 = 0;
    for (int e = 1; e < NEXP; ++e) if (aff[e] > aff[i1]) i1 = e;
    int i2 = -1;
    for (int e = 0; e < NEXP; ++e) {
      if (e == i1) continue;
      if (i2 < 0 || aff[e] > aff[i2]) i2 = e;
    }
#pragma unroll
    for (int e = 0; e < NEXP; ++e) {
      u64 key = (u64)(0xFFFFFFFFu - (unsigned)t);
      if (e == i1 || e == i2) key |= ((u64)__float_as_uint(aff[e])) << 32;
      keys[(long)e * TOKS + t] = key;
    }
  }
}

// ---------------- vectorized transpose fp32 [R][C] -> bf16 [C][R], 64x64 tiles ----------------
// Loads float4 coalesced; stores ushort8 (16B/lane) coalesced.
// PERM: orig col c -> out row ((c&1023)>>4)*32 + (c>>10)*16 + (c&15)
template <bool PERM>
__global__ __launch_bounds__(256) void k_tr64(
    const float* __restrict__ in0, const float* __restrict__ inr,
    unsigned short* __restrict__ out, int R, int C) {
  __shared__ float t[64][65];
  const int z = blockIdx.z;
  const float* in = (z == 0) ? in0 : (inr + (long)(z - 1) * R * C);
  unsigned short* o = out + (long)z * R * C;
  const int c0 = blockIdx.x * 64;
  const int r0 = blockIdx.y * 64;
  const int tid = threadIdx.x;
  const int rr = tid >> 4;          // 0..15
  const int cc4 = (tid & 15) * 4;   // 0..60
#pragma unroll
  for (int i = 0; i < 4; ++i) {
    int r = rr + 16 * i;
    float4 v = *(const float4*)&in[(long)(r0 + r) * C + c0 + cc4];
    t[r][cc4 + 0] = v.x;
    t[r][cc4 + 1] = v.y;
    t[r][cc4 + 2] = v.z;
    t[r][cc4 + 3] = v.w;
  }
  __syncthreads();
#pragma unroll
  for (int h = 0; h < 2; ++h) {
    int c = tid + h * 256;     // chunk id 0..511
    int oc = c >> 3;           // out-col-local 0..63
    int j = c & 7;             // R-chunk
    ushort8_t v8;
#pragma unroll
    for (int q = 0; q < 8; ++q) v8[q] = f2bf(t[j * 8 + q][oc]);
    int gc = c0 + oc;
    long orow = PERM ? (long)(((gc & 1023) >> 4) * 32 + ((gc >> 10) << 4) + (gc & 15))
                     : (long)gc;
    *(ushort8_t*)&o[orow * R + r0 + j * 8] = v8;
  }
}

// ---------------- per-expert radix-select of top-CAP keys + inverse map ----------------
__global__ __launch_bounds__(1024) void k_select(
    const u64* __restrict__ keys, int* __restrict__ sel,
    float* __restrict__ selw, unsigned* __restrict__ cnt,
    int* __restrict__ inv) {
  __shared__ unsigned hist[256];
  __shared__ u64 s_prefix;
  __shared__ unsigned s_k;
  __shared__ unsigned s_cnt;
  const int e = blockIdx.x;
  const u64* kk = keys + (long)e * TOKS;
  const int tid = threadIdx.x;
  if (tid == 0) { s_prefix = 0; s_k = CAP; s_cnt = 0; }
  __syncthreads();
  for (int shift = 56; shift >= 0; shift -= 8) {
    if (tid < 256) hist[tid] = 0;
    __syncthreads();
    u64 pref = s_prefix;
    for (int i = tid; i < TOKS; i += 1024) {
      u64 key = kk[i];
      bool match = (shift == 56) || ((key >> (shift + 8)) == pref);
      if (match) atomicAdd(&hist[(unsigned)(key >> shift) & 255u], 1u);
    }
    __syncthreads();
    if (tid == 0) {
      unsigned k = s_k, cum = 0;
      for (int b = 255; b >= 0; --b) {
        unsigned c = hist[b];
        if (cum + c >= k) {
          s_prefix = (s_prefix << 8) | (unsigned)b;
          s_k = k - cum;
          break;
        }
        cum += c;
      }
    }
    __syncthreads();
  }
  const u64 T = s_prefix;  // exact CAP-th largest key
  for (int i = tid; i < TOKS; i += 1024) {
    u64 key = kk[i];
    if (key >= T) {
      unsigned p = atomicAdd(&s_cnt, 1u);
      int tok = (int)(0xFFFFFFFFu - (unsigned)(key & 0xFFFFFFFFull));
      unsigned vb = (unsigned)(key >> 32);
      sel[e * CAPP + p] = tok;
      selw[e * CAPP + p] = vb ? __uint_as_float(vb) : 0.0f;
      if (vb) {
        unsigned pos = atomicAdd(&cnt[tok], 1u);
        inv[tok * 2 + pos] = e * CAPP + (int)p;
      }
    }
  }
  for (int i = CAP + tid; i < CAPP; i += 1024) {
    sel[e * CAPP + i] = 0;
    selw[e * CAPP + i] = 0.0f;
  }
}

// ---------------- combine: out[tok] = f32(o_all[tok]) + sum of routed o_all rows ----------------
__global__ __launch_bounds__(256) void k_combine(
    float* __restrict__ out, const unsigned short* __restrict__ o_all,
    const int* __restrict__ inv, const unsigned* __restrict__ cnt) {
  const int tok = blockIdx.x;
  const unsigned c = cnt[tok];
  int i0 = -1, i1 = -1;
  if (c > 0) {
    i0 = inv[tok * 2];
    if (c > 1) {
      i1 = inv[tok * 2 + 1];
      if (i1 < i0) { int t = i0; i0 = i1; i1 = t; }  // canonical order
    }
  }
  const int col = threadIdx.x * 8;
  ushort8_t s = *(const ushort8_t*)&o_all[(long)tok * DMODEL + col];
  float v[8];
#pragma unroll
  for (int q = 0; q < 8; ++q) v[q] = bf2f(s[q]);
  if (i0 >= 0) {
    ushort8_t r = *(const ushort8_t*)&o_all[(long)(TOKS + i0) * DMODEL + col];
#pragma unroll
    for (int q = 0; q < 8; ++q) v[q] += bf2f(r[q]);
  }
  if (i1 >= 0) {
    ushort8_t r = *(const ushort8_t*)&o_all[(long)(TOKS + i1) * DMODEL + col];
#pragma unroll
    for (int q = 0; q < 8; ++q) v[q] += bf2f(r[q]);
  }
  float* op = out + (long)tok * DMODEL + col;
  *(float4*)op = make_float4(v[0], v[1], v[2], v[3]);
  *(float4*)(op + 4) = make_float4(v[4], v[5], v[6], v[7]);
}

// ---------------- GEMM1: fused 256x256 8-phase (R9-proven) + SwiGLU -> a_all ----------------
__global__ __launch_bounds__(512, 2) void k_g1(
    const unsigned short* __restrict__ Abase,
    const unsigned short* __restrict__ Wbase,
    unsigned short* __restrict__ a_all, const int* __restrict__ sel) {
  constexpr int K = DMODEL;
  constexpr int N = 2048;
  constexpr int nk = K >> 6;
  extern __shared__ unsigned short lds[];  // 8 segs x 8192 shorts
  const int tid = threadIdx.x;
  const int w = tid >> 6;
  const int lane = tid & 63;

  const int bx = blockIdx.x;    // 0..7 == XCD
  const int by_u = blockIdx.y;  // 0..66

  int e, zw, m0l;
  if (by_u < 32) { e = -1; zw = 0; m0l = by_u << 8; }
  else { int q = by_u - 32; e = q / 5; zw = e + 1; m0l = (q % 5) << 8; }
  const long crow0_u = (e < 0) ? (long)m0l : (8192 + (long)e * CAPP + m0l);
  const long n0 = (long)bx * 256;
  const unsigned short* Bm = Wbase + (long)zw * N * K;

  const int wr = w >> 2;
  const int wc = w & 3;
  const int lr = lane & 15;
  const int kq = lane >> 4;

  const unsigned short* aP[2][2];
  const unsigned short* bP[2][2];
  int dstOff[2];
#pragma unroll
  for (int j = 0; j < 2; ++j) {
    int L = w * 128 + j * 64 + lane;
    int r = L >> 3;
    int cEl = ((L & 7) * 8) ^ ((r & 7) * 8);
    dstOff[j] = (w * 2 + j) * 512;
#pragma unroll
    for (int h = 0; h < 2; ++h) {
      long ar = (e < 0) ? (long)(m0l + h * 128 + r)
                        : (long)sel[e * CAPP + m0l + h * 128 + r];
      aP[h][j] = Abase + ar * (long)K + cEl;
      bP[h][j] = Bm + (n0 + h * 128 + r) * (long)K + cEl;
    }
  }

  auto STAGE = [&](int seg, int d, int ts) {
    unsigned short* base = lds + ((d << 2) + seg) * 8192;
    const unsigned short *p0, *p1;
    if (seg < 2) { p0 = aP[seg][0]; p1 = aP[seg][1]; }
    else         { p0 = bP[seg - 2][0]; p1 = bP[seg - 2][1]; }
    long ko = (long)ts * 64;
    gload_lds16(p0 + ko, base + dstOff[0]);
    gload_lds16(p1 + ko, base + dstOff[1]);
  };

  const int aSegT = wr;
  const int bSegT = 2 + (wc >> 1);
  const int colSw0 = (kq * 8) ^ ((lr & 7) * 8);
  const int colSw1 = (32 + kq * 8) ^ ((lr & 7) * 8);
  const int bRow = (wc & 1) * 64 + lr;

  STAGE(0, 0, 0); STAGE(1, 0, 0); STAGE(2, 0, 0); STAGE(3, 0, 0);
  STAGE(0, 1, 1); STAGE(1, 1, 1);
  asm volatile("s_waitcnt vmcnt(4)" ::: "memory");
  __builtin_amdgcn_sched_barrier(0);
  __builtin_amdgcn_s_barrier();
  __builtin_amdgcn_sched_barrier(0);

  f32x4 acc[8][4] = {};

#pragma unroll 1
  for (int T = 0; T < nk; ++T) {
    const int d = T & 1, dn = d ^ 1;
    int t1 = T + 1; if (t1 >= nk) t1 -= nk;
    int t2 = T + 2; if (t2 >= nk) t2 -= nk;
    const unsigned short* aSeg = lds + ((d << 2) + aSegT) * 8192;
    const unsigned short* bSeg = lds + ((d << 2) + bSegT) * 8192;
    bf16x8 af[8], b0, b1;

    // phase 0
#pragma unroll
    for (int m = 0; m < 8; ++m)
      af[m] = *(const bf16x8*)&aSeg[(m * 16 + lr) * 64 + colSw0];
    b0 = *(const bf16x8*)&bSeg[(bRow + 0) * 64 + colSw0];
    b1 = *(const bf16x8*)&bSeg[(bRow + 16) * 64 + colSw0];
    __builtin_amdgcn_sched_barrier(0);
    STAGE(2, dn, t1);
    __builtin_amdgcn_sched_barrier(0);
    __builtin_amdgcn_s_barrier();
    asm volatile("s_waitcnt lgkmcnt(0)" ::: "memory");
    __builtin_amdgcn_sched_barrier(0);
    __builtin_amdgcn_s_setprio(1);
#pragma unroll
    for (int m = 0; m < 8; ++m) {
      acc[m][0] = MFMA16(af[m], b0, acc[m][0]);
      acc[m][1] = MFMA16(af[m], b1, acc[m][1]);
    }
    __builtin_amdgcn_s_setprio(0);
    __builtin_amdgcn_sched_barrier(0);
    __builtin_amdgcn_s_barrier();
    __builtin_amdgcn_sched_barrier(0);

    // phase 1
    b0 = *(const bf16x8*)&bSeg[(bRow + 32) * 64 + colSw0];
    b1 = *(const bf16x8*)&bSeg[(bRow + 48) * 64 + colSw0];
    __builtin_amdgcn_sched_barrier(0);
    STAGE(3, dn, t1);
    __builtin_amdgcn_sched_barrier(0);
    __builtin_amdgcn_s_barrier();
    asm volatile("s_waitcnt lgkmcnt(0)" ::: "memory");
    __builtin_amdgcn_sched_barrier(0);
    __builtin_amdgcn_s_setprio(1);
#pragma unroll
    for (int m = 0; m < 8; ++m) {
      acc[m][2] = MFMA16(af[m], b0, acc[m][2]);
      acc[m][3] = MFMA16(af[m], b1, acc[m][3]);
    }
    __builtin_amdgcn_s_setprio(0);
    __builtin_amdgcn_sched_barrier(0);
    __builtin_amdgcn_s_barrier();
    __builtin_amdgcn_sched_barrier(0);

    // phase 2
#pragma unroll
    for (int m = 0; m < 8; ++m)
      af[m] = *(const bf16x8*)&aSeg[(m * 16 + lr) * 64 + colSw1];
    b0 = *(const bf16x8*)&bSeg[(bRow + 0) * 64 + colSw1];
    b1 = *(const bf16x8*)&bSeg[(bRow + 16) * 64 + colSw1];
    __builtin_amdgcn_sched_barrier(0);
    __builtin_amdgcn_s_barrier();
    asm volatile("s_waitcnt lgkmcnt(0)" ::: "memory");
    __builtin_amdgcn_sched_barrier(0);
    __builtin_amdgcn_s_setprio(1);
#pragma unroll
    for (int m = 0; m < 8; ++m) {
      acc[m][0] = MFMA16(af[m], b0, acc[m][0]);
      acc[m][1] = MFMA16(af[m], b1, acc[m][1]);
    }
    __builtin_amdgcn_s_setprio(0);
    __builtin_amdgcn_sched_barrier(0);
    __builtin_amdgcn_s_barrier();
    __builtin_amdgcn_sched_barrier(0);

    // phase 3
    b0 = *(const bf16x8*)&bSeg[(bRow + 32) * 64 + colSw1];
    b1 = *(const bf16x8*)&bSeg[(bRow + 48) * 64 + colSw1];
    __builtin_amdgcn_sched_barrier(0);
    STAGE(0, d, t2);
    STAGE(1, d, t2);
    asm volatile("s_waitcnt vmcnt(4)" ::: "memory");
    __builtin_amdgcn_sched_barrier(0);
    __builtin_amdgcn_s_barrier();
    asm volatile("s_waitcnt lgkmcnt(0)" ::: "memory");
    __builtin_amdgcn_sched_barrier(0);
    __builtin_amdgcn_s_setprio(1);
#pragma unroll
    for (int m = 0; m < 8; ++m) {
      acc[m][2] = MFMA16(af[m], b0, acc[m][2]);
      acc[m][3] = MFMA16(af[m], b1, acc[m][3]);
    }
    __builtin_amdgcn_s_setprio(0);
    __builtin_amdgcn_sched_barrier(0);
    __builtin_amdgcn_s_barrier();
    __builtin_amdgcn_sched_barrier(0);
  }
  asm volatile("s_waitcnt vmcnt(0)" ::: "memory");

  // SwiGLU epilogue -> a_all bf16 [17152][FD]
  const int r0q = (lane >> 4) * 4;
  const int cc = lane & 15;
  const long gcol0 = (n0 >> 1) + wc * 32;
#pragma unroll
  for (int m = 0; m < 8; ++m)
#pragma unroll
    for (int rj = 0; rj < 4; ++rj) {
      long row = crow0_u + wr * 128 + m * 16 + r0q + rj;
#pragma unroll
      for (int q2 = 0; q2 < 2; ++q2) {
        float x1v = acc[m][2 * q2][rj];
        float x2v = acc[m][2 * q2 + 1][rj];
        float s = x2v / (1.0f + __expf(-x2v));
        a_all[row * FD + gcol0 + q2 * 16 + cc] = f2bf(x1v * s);
      }
    }
}

// ---------------- GEMM2: 128x128 2-phase, 4 blk/CU (R7-proven), unified bf16 epilogue ----------------
// a_all[17152,1024] @ w2t[zw]^T -> o_all bf16 [17152][2048]; routed rows scaled by selw.
__global__ __launch_bounds__(512, 4) void k_g2(
    const unsigned short* __restrict__ Abase,
    const unsigned short* __restrict__ Wbase,
    unsigned short* __restrict__ o_all, const float* __restrict__ selw) {
  constexpr int K = FD;
  constexpr int N = DMODEL;
  constexpr int nk = K >> 5;
  __shared__ unsigned short lds[2][8192];
  const int tid = threadIdx.x & 255;
  const int isUpper = 0;  // 256-thread kernel shape below
  (void)isUpper;
  const int w = tid >> 6;
  const int lane = tid & 63;

  // locality swizzle over grid (16,134): per-XCD 268-tile run, supertiles 8x16 col-outer
  int lin = blockIdx.x + ((int)blockIdx.y << 4);
  int gt = (lin & 7) * 268 + (lin >> 3);
  int ct, rt, su;
  if (gt < 2048) { su = gt >> 7; int rr = gt & 127; ct = rr >> 3; rt = rr & 7; }
  else           { su = 16;      int rr = gt - 2048; ct = rr / 6; rt = rr % 6; }
  const int by_u = su * 8 + rt;  // 0..133
  const int bx = ct;             // 0..15

  int e, zw, m0l;
  if (by_u < 64) { e = -1; zw = 0; m0l = by_u << 7; }
  else { int q = by_u - 64; e = q / 10; zw = e + 1; m0l = (q % 10) << 7; }
  const long crow0_u = (e < 0) ? (long)m0l : (8192 + (long)e * CAPP + m0l);
  const long n0 = (long)bx * 128;
  const unsigned short* Bm = Wbase + (long)zw * N * K;

  // staging: 4 chunks/thread (2 A + 2 B), pre-swizzled source col
  const int r_ = (w << 4) + (lane >> 2);
  const int p_ = lane & 3;
  const unsigned short* aSrc[2];
  const unsigned short* bSrc[2];
#pragma unroll
  for (int c = 0; c < 2; ++c) {
    int rsg = c * 64 + r_;
    int q = p_ ^ ((rsg >> 1) & 3);
    aSrc[c] = Abase + (crow0_u + rsg) * (long)K + q * 8;
    bSrc[c] = Bm + (n0 + rsg) * (long)K + q * 8;
  }
  const int dst0 = tid * 8;

  auto STAGE = [&](int buf, int kt) {
    const long ko = (long)kt * 32;
#pragma unroll
    for (int c = 0; c < 2; ++c) {
      gload_lds16(aSrc[c] + ko, &lds[buf][c * 2048 + dst0]);
      gload_lds16(bSrc[c] + ko, &lds[buf][4096 + c * 2048 + dst0]);
    }
  };

  const int wr = w >> 1, wc = w & 1;
  const int lr = lane & 15, kq = lane >> 4;
  const int slot = (kq ^ ((lr >> 1) & 3)) * 8;
  const int aRow = wr * 64 + lr;
  const int bRow = wc * 64 + lr;

  STAGE(0, 0);
  asm volatile("s_waitcnt vmcnt(0)" ::: "memory");
  __builtin_amdgcn_sched_barrier(0);
  __builtin_amdgcn_s_barrier();
  __builtin_amdgcn_sched_barrier(0);

  f32x4 acc[4][4] = {};
  int cur = 0;

#pragma unroll 1
  for (int kt = 0; kt < nk; ++kt) {
    if (kt + 1 < nk) STAGE(cur ^ 1, kt + 1);
    const unsigned short* aSeg = &lds[cur][0];
    const unsigned short* bSeg = &lds[cur][4096];
    bf16x8 af[4], bf[4];
#pragma unroll
    for (int m = 0; m < 4; ++m)
      af[m] = *(const bf16x8*)&aSeg[(aRow + m * 16) * 32 + slot];
#pragma unroll
    for (int n = 0; n < 4; ++n)
      bf[n] = *(const bf16x8*)&bSeg[(bRow + n * 16) * 32 + slot];
    asm volatile("s_waitcnt lgkmcnt(0)" ::: "memory");
    __builtin_amdgcn_sched_barrier(0);
    __builtin_amdgcn_s_setprio(1);
#pragma unroll
    for (int m = 0; m < 4; ++m)
#pragma unroll
      for (int n = 0; n < 4; ++n)
        acc[m][n] = MFMA16(af[m], bf[n], acc[m][n]);
    __builtin_amdgcn_s_setprio(0);
    asm volatile("s_waitcnt vmcnt(0)" ::: "memory");
    __builtin_amdgcn_sched_barrier(0);
    __builtin_amdgcn_s_barrier();
    __builtin_amdgcn_sched_barrier(0);
    cur ^= 1;
  }

  // unified bf16 epilogue: shared rows w=1, routed rows w=selw
  const int r0q = (lane >> 4) * 4;
  const int cc = lane & 15;
  const long ccol0 = n0 + wc * 64;
#pragma unroll
  for (int m = 0; m < 4; ++m)
#pragma unroll
    for (int rj = 0; rj < 4; ++rj) {
      int lrow = m0l + wr * 64 + m * 16 + r0q + rj;
      float wgt = (e < 0) ? 1.0f : selw[e * CAPP + (lrow - m0l) + (m0l)];
      // note: lrow is local within expert block for routed (m0l..m0l+127)
      long row = crow0_u + wr * 64 + m * 16 + r0q + rj;
#pragma unroll
      for (int n = 0; n < 4; ++n)
        o_all[row * DMODEL + ccol0 + n * 16 + cc] = f2bf(acc[m][n][rj] * wgt);
    }
}

extern "C" void kernel_launch(void* const* d_in, const int* in_sizes, int n_in,
                              void* d_out, int out_size, void* d_ws,
                              size_t ws_size, hipStream_t stream) {
  (void)in_sizes; (void)n_in; (void)out_size; (void)ws_size;
  const float* x = (const float*)d_in[0];
  const float* gw = (const float*)d_in[1];
  const float* eb = (const float*)d_in[2];
  const float* sw1 = (const float*)d_in[3];
  const float* sw2 = (const float*)d_in[4];
  const float* rw1 = (const float*)d_in[5];
  const float* rw2 = (const float*)d_in[6];
  float* out = (float*)d_out;

  char* ws = (char*)d_ws;
  size_t off = 0;
  auto alloc = [&](size_t bytes) {
    size_t o = off;
    off += (bytes + 255) & ~(size_t)255;
    return o;
  };
  unsigned short* xb    = (unsigned short*)(ws + alloc((size_t)TOKS * DMODEL * 2));
  unsigned short* w1t   = (unsigned short*)(ws + alloc((size_t)8 * DMODEL * (2 * FD) * 2));
  unsigned short* w2t   = (unsigned short*)(ws + alloc((size_t)8 * DMODEL * FD * 2));
  unsigned short* a_all = (unsigned short*)(ws + alloc((size_t)(TOKS + NEXP * CAPP) * FD * 2));
  unsigned short* o_all = (unsigned short*)(ws + alloc((size_t)(TOKS + NEXP * CAPP) * DMODEL * 2));
  u64* keys = (u64*)(ws + alloc((size_t)NEXP * TOKS * 8));
  int* sel  = (int*)(ws + alloc((size_t)NEXP * CAPP * 4));
  float* selw = (float*)(ws + alloc((size_t)NEXP * CAPP * 4));
  unsigned* cnt = (unsigned*)(ws + alloc((size_t)TOKS * 4));
  int* inv = (int*)(ws + alloc((size_t)TOKS * 2 * 4));

  const size_t LDSB = 131072;

  // 1. fused convert + gating
  k_conv_gate<<<TOKS, 256, 0, stream>>>(x, gw, eb, xb, keys);
  // 2./3. vectorized weight transposes (w1 with x1/x2 16-block interleave)
  k_tr64<true><<<dim3(32, 32, 8), 256, 0, stream>>>(sw1, rw1, w1t, DMODEL, 2 * FD);
  k_tr64<false><<<dim3(32, 16, 8), 256, 0, stream>>>(sw2, rw2, w2t, FD, DMODEL);
  // 4. per-expert selection + inverse map
  hipMemsetAsync(cnt, 0, (size_t)TOKS * 4, stream);
  k_select<<<NEXP, 1024, 0, stream>>>(keys, sel, selw, cnt, inv);
  // 5. GEMM1 (8-phase 256^2) + SwiGLU -> a_all
  k_g1<<<dim3(8, URT256), 512, LDSB, stream>>>(xb, w1t, a_all, sel);
  // 6. GEMM2 (2-phase 128^2, 4 blk/CU) -> o_all bf16 (shared unweighted, routed weighted)
  k_g2<<<dim3(16, URT128), 256, 0, stream>>>(a_all, w2t, o_all, selw);
  // 7. combine -> out fp32 (full overwrite)
  k_combine<<<TOKS, 256, 0, stream>>>(out, o_all, inv, cnt);
}